// Round 4
// baseline (1162.498 us; speedup 1.0000x reference)
//
#include <hip/hip_runtime.h>
#include <stdint.h>
#include <stddef.h>

typedef __attribute__((ext_vector_type(8))) short short8;
typedef __attribute__((ext_vector_type(4))) float f32x4;
typedef unsigned short u16;
typedef unsigned int u32;

#define DEVI __device__ __forceinline__

static constexpr int T_ = 1024, C_ = 1024, M_ = 2048; // M = B*T

DEVI float bf2f(u16 u){ u32 x=((u32)u)<<16; float f; __builtin_memcpy(&f,&x,4); return f; }
DEVI u16 f2bf(float f){ u32 x; __builtin_memcpy(&x,&f,4); x += 0x7fffu + ((x>>16)&1u); return (u16)(x>>16); }

DEVI void gld_lds16(const u16* g, u16* l){
  __builtin_amdgcn_global_load_lds((const __attribute__((address_space(1))) void*)g,
                                   (__attribute__((address_space(3))) void*)l, 16, 0, 0);
}
DEVI f32x4 mfma16(short8 a, short8 b, f32x4 c){
  return __builtin_amdgcn_mfma_f32_16x16x32_bf16(a, b, c, 0, 0, 0);
}

// ---------------- cast f32 -> bf16 (4 elem / thread) ----------------
__global__ void k_cast(const float* __restrict__ in, u16* __restrict__ out){
  int i = (blockIdx.x*blockDim.x + threadIdx.x)*4;
  float4 v = *(const float4*)(in+i);
  uint2 o; o.x = (u32)f2bf(v.x) | ((u32)f2bf(v.y)<<16);
  o.y = (u32)f2bf(v.z) | ((u32)f2bf(v.w)<<16);
  *(uint2*)(out+i) = o;
}

// ---------------- rope tables ----------------
__global__ void k_tables(float* __restrict__ cosT, float* __restrict__ sinT){
  int i = blockIdx.x*256 + threadIdx.x;
  int t = i>>5, f = i&31;
  float inv = expf(-((float)f/32.f)*9.210340371976184f); // 10000^(-f/32)
  float fr = (float)t * inv;
  cosT[i] = cosf(fr); sinT[i] = sinf(fr);
}

// ---------------- rms (or plain cast) f32 -> bf16, row = 1024 ----------------
template<int NORM>
__global__ void k_rms(const float* __restrict__ x, u16* __restrict__ out){
  __shared__ float ps[4];
  int row = blockIdx.x, tid = threadIdx.x;
  float4 v = ((const float4*)(x + (size_t)row*C_))[tid];
  if (NORM){
    float ss = v.x*v.x+v.y*v.y+v.z*v.z+v.w*v.w;
    #pragma unroll
    for(int o=32;o>=1;o>>=1) ss += __shfl_xor(ss,o);
    if((tid&63)==0) ps[tid>>6]=ss;
    __syncthreads();
    ss = ps[0]+ps[1]+ps[2]+ps[3];
    float r = rsqrtf(ss*(1.f/C_) + 1e-6f);
    v.x*=r; v.y*=r; v.z*=r; v.w*=r;
  }
  uint2 o; o.x=(u32)f2bf(v.x)|((u32)f2bf(v.y)<<16);
  o.y=(u32)f2bf(v.z)|((u32)f2bf(v.w)<<16);
  ((uint2*)(out + (size_t)row*C_))[tid] = o;
}

// ---------------- GEMM: C[m,n] = sum_k A[m,k]*B[n,k]; A(MxK), B(NxK) bf16 ----------------
// EPI 0: bf16 out; 1: f32 out = Res + acc; 2: f32 out = acc
template<int EPI>
__global__ __launch_bounds__(256) void k_gemm(const u16* __restrict__ A, const u16* __restrict__ Bw,
    void* __restrict__ Cout, const float* __restrict__ Res, int M, int N, int K){
  __shared__ u16 As[128*32];
  __shared__ u16 Bs[128*32];
  const int tid = threadIdx.x, w = tid>>6, lane = tid&63;
  const int bm = blockIdx.y<<7, bn = blockIdx.x<<7;
  const int wr = w>>1, wc = w&1;
  const int sr = lane>>2, sc = lane&3;
  f32x4 acc[4][4] = {};
  const u16* ga0 = A  + (size_t)(bm + w*32 + sr)*K + sc*8;
  const u16* gb0 = Bw + (size_t)(bn + w*32 + sr)*K + sc*8;
  u16* la0 = &As[(w*32)*32];
  u16* lb0 = &Bs[(w*32)*32];
  const int r16 = lane&15, ko = (lane>>4)*8;
  for (int k0=0; k0<K; k0+=32){
    __syncthreads();
    gld_lds16(ga0 + k0, la0);
    gld_lds16(ga0 + (size_t)16*K + k0, la0 + 16*32);
    gld_lds16(gb0 + k0, lb0);
    gld_lds16(gb0 + (size_t)16*K + k0, lb0 + 16*32);
    __syncthreads();
    short8 af[4], bf[4];
    #pragma unroll
    for(int mf=0;mf<4;++mf) af[mf] = *(const short8*)&As[(wr*64+mf*16+r16)*32 + ko];
    #pragma unroll
    for(int nf=0;nf<4;++nf) bf[nf] = *(const short8*)&Bs[(wc*64+nf*16+r16)*32 + ko];
    #pragma unroll
    for(int mf=0;mf<4;++mf)
      #pragma unroll
      for(int nf=0;nf<4;++nf)
        acc[mf][nf] = mfma16(af[mf], bf[nf], acc[mf][nf]);
  }
  const int rr = (lane>>4)*4;
  #pragma unroll
  for(int mf=0;mf<4;++mf){
    #pragma unroll
    for(int nf=0;nf<4;++nf){
      #pragma unroll
      for(int r=0;r<4;++r){
        size_t idx = (size_t)(bm + wr*64 + mf*16 + rr + r)*N + (bn + wc*64 + nf*16 + r16);
        float val = acc[mf][nf][r];
        if (EPI==0)      ((u16*)Cout)[idx] = f2bf(val);
        else if (EPI==1) ((float*)Cout)[idx] = Res[idx] + val;
        else             ((float*)Cout)[idx] = val;
      }
    }
  }
}

// ---------------- rope on q,k (+ optional l2norm*sqk for sph); writes (BH,T,64) ----------------
template<int SPH>
__global__ void k_ropeqk(const u16* __restrict__ qkv, const float* __restrict__ cosT,
                         const float* __restrict__ sinT, const float* __restrict__ sqk,
                         u16* __restrict__ Qb, u16* __restrict__ Kb){
  int idx = blockIdx.x*4 + (threadIdx.x>>6);
  int lane = threadIdx.x&63;
  int bh = idx>>10, t = idx&1023;
  int b = bh>>4, h = bh&15;
  size_t qa = (size_t)(b*T_ + t)*3072 + h*64 + lane;
  float qv = bf2f(qkv[qa]), kv = bf2f(qkv[qa + 1024]);
  float c = cosT[t*32 + (lane&31)], s = sinT[t*32 + (lane&31)];
  float qo = __shfl(qv, lane^32), ko2 = __shfl(kv, lane^32);
  // lane<32: x1*c + x2*s ; lane>=32: -x1*s + x2*c  (x1=low half, x2=high half)
  float qr = (lane<32) ? (qv*c + qo*s) : (qv*c - qo*s);
  float kr = (lane<32) ? (kv*c + ko2*s) : (kv*c - ko2*s);
  if (SPH){
    float sq = qr*qr, sk = kr*kr;
    #pragma unroll
    for(int o=32;o>=1;o>>=1){ sq += __shfl_xor(sq,o); sk += __shfl_xor(sk,o); }
    float sc2 = sqk[h*64+lane]*32.f;
    qr = qr / fmaxf(sqrtf(sq),1e-12f) * sc2;
    kr = kr / fmaxf(sqrtf(sk),1e-12f) * sc2;
  }
  size_t oa = (size_t)bh*T_*64 + (size_t)t*64 + lane;
  Qb[oa] = f2bf(qr); Kb[oa] = f2bf(kr);
}

// ---------------- V transpose: qkv v-part -> (BH, 64, T) ----------------
__global__ void k_vtrans(const u16* __restrict__ qkv, u16* __restrict__ Vt){
  __shared__ u16 tile[64][68];
  int bh = blockIdx.x, t0 = blockIdx.y*64;
  int b = bh>>4, h = bh&15;
  int tid = threadIdx.x;
  int tt = tid>>2, ch = tid&3;
  const u16* src = qkv + (size_t)(b*T_ + t0 + tt)*3072 + 2048 + h*64 + ch*16;
  short8 v0 = *(const short8*)src;
  short8 v1 = *(const short8*)(src+8);
  #pragma unroll
  for(int j=0;j<8;++j){ tile[tt][ch*16+j]=(u16)v0[j]; tile[tt][ch*16+8+j]=(u16)v1[j]; }
  __syncthreads();
  int d = tid>>2, tc = (tid&3)*16;
  short8 a, bb;
  #pragma unroll
  for(int j=0;j<8;++j){ a[j]=(short)tile[tc+j][d]; bb[j]=(short)tile[tc+8+j][d]; }
  u16* dst = Vt + ((size_t)bh*64 + d)*T_ + t0 + tc;
  *(short8*)dst = a; *(short8*)(dst+8) = bb;
}

// ---------------- flash attention, 1 wave / 16 q-rows. GEOM: 0 euc, 1 hyp, 2 sph ----------------
template<int GEOM>
__global__ __launch_bounds__(64) void k_attn(const u16* __restrict__ Q, const u16* __restrict__ K,
    const u16* __restrict__ Vt, const float* __restrict__ khyp, u16* __restrict__ Oo){
  __shared__ u16 P[16*32];
  int qt = blockIdx.x, bh = blockIdx.y;
  int b = bh>>4, h = bh&15;
  int lane = threadIdx.x;
  int r16 = lane&15, g = lane>>4, ko = g*8;
  const u16* Qp = Q + (size_t)bh*T_*64;
  const u16* Kp = K + (size_t)bh*T_*64;
  const u16* Vp = Vt + (size_t)bh*64*T_;
  short8 qf0 = *(const short8*)&Qp[(size_t)(qt*16 + r16)*64 + ko];
  short8 qf1 = *(const short8*)&Qp[(size_t)(qt*16 + r16)*64 + 32 + ko];
  float kc=1.f, sqkc=1.f, tqr[4];
  if (GEOM==1){
    kc = khyp[h]; sqkc = sqrtf(kc);
    float ss=0;
    #pragma unroll
    for(int j=0;j<8;++j){ float a=bf2f((u16)qf0[j]); ss+=a*a; a=bf2f((u16)qf1[j]); ss+=a*a; }
    ss += __shfl_xor(ss,16); ss += __shfl_xor(ss,32);
    float tq = sqrtf(kc + ss);
    #pragma unroll
    for(int r=0;r<4;++r) tqr[r] = __shfl(tq, g*4+r);
  }
  f32x4 of[4] = {};
  float m[4], l[4];
  #pragma unroll
  for(int r=0;r<4;++r){ m[r]=-1e30f; l[r]=0.f; }
  int ntiles = (qt*16 + 16 + 31)>>5;
  for(int it=0; it<ntiles; ++it){
    int kt = it*32;
    short8 kf00 = *(const short8*)&Kp[(size_t)(kt + r16)*64 + ko];
    short8 kf01 = *(const short8*)&Kp[(size_t)(kt + r16)*64 + 32 + ko];
    short8 kf10 = *(const short8*)&Kp[(size_t)(kt + 16 + r16)*64 + ko];
    short8 kf11 = *(const short8*)&Kp[(size_t)(kt + 16 + r16)*64 + 32 + ko];
    f32x4 s0={}, s1={};
    s0 = mfma16(qf0, kf00, s0); s0 = mfma16(qf1, kf01, s0);
    s1 = mfma16(qf0, kf10, s1); s1 = mfma16(qf1, kf11, s1);
    float tk0=0.f, tk1=0.f;
    if (GEOM==1){
      float ss0=0, ss1=0;
      #pragma unroll
      for(int j=0;j<8;++j){
        float a=bf2f((u16)kf00[j]); ss0+=a*a; a=bf2f((u16)kf01[j]); ss0+=a*a;
        a=bf2f((u16)kf10[j]); ss1+=a*a; a=bf2f((u16)kf11[j]); ss1+=a*a;
      }
      ss0 += __shfl_xor(ss0,16); ss0 += __shfl_xor(ss0,32);
      ss1 += __shfl_xor(ss1,16); ss1 += __shfl_xor(ss1,32);
      tk0 = sqrtf(kc+ss0); tk1 = sqrtf(kc+ss1);
    }
    float w0[4], w1[4];
    #pragma unroll
    for(int r=0;r<4;++r){
      int qg = qt*16 + g*4 + r;
      float a0, a1;
      if (GEOM==0){ a0 = s0[r]*(1.f/32.f); a1 = s1[r]*(1.f/32.f); }
      else if (GEOM==2){ a0 = s0[r]*32.f; a1 = s1[r]*32.f; }
      else {
        float z0 = (tqr[r]*tk0 - s0[r])/kc; z0 = fmaxf(z0, 1.f+1e-7f);
        float z1 = (tqr[r]*tk1 - s1[r])/kc; z1 = fmaxf(z1, 1.f+1e-7f);
        float d0 = sqkc * logf(z0 + sqrtf(z0*z0 - 1.f));
        float d1 = sqkc * logf(z1 + sqrtf(z1*z1 - 1.f));
        a0 = 1.f/(1e-6f + d0); a1 = 1.f/(1e-6f + d1);
      }
      if (kt + r16 > qg)      a0 = -1e30f;
      if (kt + 16 + r16 > qg) a1 = -1e30f;
      w0[r]=a0; w1[r]=a1;
    }
    #pragma unroll
    for(int r=0;r<4;++r){
      float mt = fmaxf(w0[r], w1[r]);
      #pragma unroll
      for(int o=1;o<16;o<<=1) mt = fmaxf(mt, __shfl_xor(mt,o));
      float mn = fmaxf(m[r], mt);
      float alpha = __expf(m[r]-mn);
      m[r]=mn;
      float p0 = __expf(w0[r]-mn), p1 = __expf(w1[r]-mn);
      float rs = p0+p1;
      #pragma unroll
      for(int o=1;o<16;o<<=1) rs += __shfl_xor(rs,o);
      l[r] = l[r]*alpha + rs;
      #pragma unroll
      for(int vb=0;vb<4;++vb) of[vb][r] *= alpha;
      P[(g*4+r)*32 + r16]      = f2bf(p0);
      P[(g*4+r)*32 + 16 + r16] = f2bf(p1);
    }
    __syncthreads();
    short8 pf = *(const short8*)&P[r16*32 + ko];
    #pragma unroll
    for(int vb=0;vb<4;++vb){
      short8 vf = *(const short8*)&Vp[(size_t)(vb*16 + r16)*T_ + kt + ko];
      of[vb] = mfma16(pf, vf, of[vb]);
    }
    __syncthreads();
  }
  #pragma unroll
  for(int vb=0;vb<4;++vb){
    #pragma unroll
    for(int r=0;r<4;++r){
      int t = qt*16 + g*4 + r;
      Oo[((size_t)(b*T_ + t))*C_ + h*64 + vb*16 + r16] = f2bf(of[vb][r] / l[r]);
    }
  }
}

// ---------------- silu-mul (optionally * suv*32) bf16 ----------------
template<int SUV>
__global__ void k_silu(const u16* __restrict__ uv, const float* __restrict__ suv, u16* __restrict__ g){
  int i = blockIdx.x*256 + threadIdx.x;
  int m = i>>10, j = (i&1023)*4;
  const u16* up = uv + (size_t)m*8192 + j;
  uint2 uu = *(const uint2*)up;
  uint2 vv = *(const uint2*)(up+4096);
  float u[4] = { bf2f((u16)(uu.x&0xffff)), bf2f((u16)(uu.x>>16)), bf2f((u16)(uu.y&0xffff)), bf2f((u16)(uu.y>>16)) };
  float v[4] = { bf2f((u16)(vv.x&0xffff)), bf2f((u16)(vv.x>>16)), bf2f((u16)(vv.y&0xffff)), bf2f((u16)(vv.y>>16)) };
  float o[4];
  #pragma unroll
  for(int e=0;e<4;++e){
    float ue=u[e], ve=v[e];
    if (SUV){ ue *= suv[j+e]*32.0f; ve *= suv[4096+j+e]*32.0f; }
    o[e] = ue * (ve / (1.0f + __expf(-ve)));
  }
  uint2 oo; oo.x=(u32)f2bf(o[0])|((u32)f2bf(o[1])<<16); oo.y=(u32)f2bf(o[2])|((u32)f2bf(o[3])<<16);
  *(uint2*)(g + (size_t)m*4096 + j) = oo;
}

// ---------------- spherical skip: out = l2n(l2n(x) + lr*(l2n(h)-l2n(x))) ----------------
__global__ void k_sphskip(const float* __restrict__ x, const float* __restrict__ hh,
                          const float* __restrict__ alpha, float* __restrict__ out){
  __shared__ float red[3][4];
  int row = blockIdx.x, tid = threadIdx.x;
  float4 xv = ((const float4*)(x  + (size_t)row*C_))[tid];
  float4 hv = ((const float4*)(hh + (size_t)row*C_))[tid];
  float ssx = xv.x*xv.x+xv.y*xv.y+xv.z*xv.z+xv.w*xv.w;
  float ssh = hv.x*hv.x+hv.y*hv.y+hv.z*hv.z+hv.w*hv.w;
  #pragma unroll
  for(int o=32;o>=1;o>>=1){ ssx += __shfl_xor(ssx,o); ssh += __shfl_xor(ssh,o); }
  if((tid&63)==0){ red[0][tid>>6]=ssx; red[1][tid>>6]=ssh; }
  __syncthreads();
  ssx = red[0][0]+red[0][1]+red[0][2]+red[0][3];
  ssh = red[1][0]+red[1][1]+red[1][2]+red[1][3];
  float rx = 1.f/fmaxf(sqrtf(ssx),1e-12f), rh = 1.f/fmaxf(sqrtf(ssh),1e-12f);
  float4 al = ((const float4*)alpha)[tid];
  float y[4]; float ssy=0.f;
  { float a0=xv.x*rx, b0=hv.x*rh, lr=fabsf(al.x*1.6f); y[0]=a0+lr*(b0-a0); ssy+=y[0]*y[0]; }
  { float a0=xv.y*rx, b0=hv.y*rh, lr=fabsf(al.y*1.6f); y[1]=a0+lr*(b0-a0); ssy+=y[1]*y[1]; }
  { float a0=xv.z*rx, b0=hv.z*rh, lr=fabsf(al.z*1.6f); y[2]=a0+lr*(b0-a0); ssy+=y[2]*y[2]; }
  { float a0=xv.w*rx, b0=hv.w*rh, lr=fabsf(al.w*1.6f); y[3]=a0+lr*(b0-a0); ssy+=y[3]*y[3]; }
  #pragma unroll
  for(int o=32;o>=1;o>>=1) ssy += __shfl_xor(ssy,o);
  if((tid&63)==0) red[2][tid>>6]=ssy;
  __syncthreads();
  ssy = red[2][0]+red[2][1]+red[2][2]+red[2][3];
  float ry = 1.f/fmaxf(sqrtf(ssy),1e-12f);
  float4 o4; o4.x=y[0]*ry; o4.y=y[1]*ry; o4.z=y[2]*ry; o4.w=y[3]*ry;
  ((float4*)(out + (size_t)row*C_))[tid] = o4;
}

extern "C" void kernel_launch(void* const* d_in, const int* in_sizes, int n_in,
                              void* d_out, int out_size, void* d_ws, size_t ws_size,
                              hipStream_t stream){
  (void)n_in; (void)out_size; (void)ws_size;
  // dict order: x, [Wqkv,Wo,Wuv,Wmo] x {euc,hyp,sph}, k_hyp, sqk, suv, attn_alpha, mlp_alpha
  int i_khyp, sphb;
  if (in_sizes[9]==16){ i_khyp=9; sphb=10; } else { i_khyp=13; sphb=9; }
  const float* Wq[3] = {(const float*)d_in[1], (const float*)d_in[5], (const float*)d_in[sphb+0]};
  const float* Wo[3] = {(const float*)d_in[2], (const float*)d_in[6], (const float*)d_in[sphb+1]};
  const float* Wu[3] = {(const float*)d_in[3], (const float*)d_in[7], (const float*)d_in[sphb+2]};
  const float* Wm[3] = {(const float*)d_in[4], (const float*)d_in[8], (const float*)d_in[sphb+3]};
  const float* khyp = (const float*)d_in[i_khyp];
  const float* sqk  = (const float*)d_in[14];
  const float* suv  = (const float*)d_in[15];
  const float* aal  = (const float*)d_in[16];
  const float* mal  = (const float*)d_in[17];

  char* p = (char*)d_ws;
  auto alloc = [&](size_t bytes)->char*{ char* r=p; p += (bytes+255)&~(size_t)255; return r; };
  float* x    = (float*)alloc((size_t)M_*C_*4);
  float* hf32 = (float*)alloc((size_t)M_*C_*4);
  u16* h_bf   = (u16*)alloc((size_t)M_*C_*2);
  u16* qkv    = (u16*)alloc((size_t)M_*3072*2);
  u16* Qb     = (u16*)alloc((size_t)M_*1024*2);
  u16* Kb     = (u16*)alloc((size_t)M_*1024*2);
  u16* Vt     = (u16*)alloc((size_t)M_*1024*2);
  u16* att    = (u16*)alloc((size_t)M_*1024*2);
  u16* uvb    = (u16*)alloc((size_t)M_*8192*2);
  u16* gb     = (u16*)alloc((size_t)M_*4096*2);
  u16* wqb    = (u16*)alloc((size_t)3*C_*C_*2);
  u16* wob    = (u16*)alloc((size_t)C_*C_*2);
  u16* wub    = (u16*)alloc((size_t)8*C_*C_*2);
  u16* wmb    = (u16*)alloc((size_t)4*C_*C_*2);
  float* cosT = (float*)alloc((size_t)T_*32*4);
  float* sinT = (float*)alloc((size_t)T_*32*4);

  hipMemcpyAsync(x, d_in[0], (size_t)M_*C_*4, hipMemcpyDeviceToDevice, stream);
  k_tables<<<T_*32/256, 256, 0, stream>>>(cosT, sinT);

  for (int gi=0; gi<3; ++gi){
    bool sph = (gi==2);
    k_cast<<<3*C_*C_/1024, 256, 0, stream>>>(Wq[gi], wqb);
    k_cast<<<  C_*C_/1024, 256, 0, stream>>>(Wo[gi], wob);
    k_cast<<<8*C_*C_/1024, 256, 0, stream>>>(Wu[gi], wub);
    k_cast<<<4*C_*C_/1024, 256, 0, stream>>>(Wm[gi], wmb);

    if (!sph) k_rms<1><<<M_,256,0,stream>>>(x, h_bf);
    else      k_rms<0><<<M_,256,0,stream>>>(x, h_bf);
    k_gemm<0><<<dim3(24,16),256,0,stream>>>(h_bf, wqb, qkv, nullptr, M_, 3072, 1024);
    if (sph) k_ropeqk<1><<<8192,256,0,stream>>>(qkv, cosT, sinT, sqk, Qb, Kb);
    else     k_ropeqk<0><<<8192,256,0,stream>>>(qkv, cosT, sinT, nullptr, Qb, Kb);
    k_vtrans<<<dim3(32,16),256,0,stream>>>(qkv, Vt);
    if (gi==0)      k_attn<0><<<dim3(64,32),64,0,stream>>>(Qb,Kb,Vt,nullptr,att);
    else if (gi==1) k_attn<1><<<dim3(64,32),64,0,stream>>>(Qb,Kb,Vt,khyp,att);
    else            k_attn<2><<<dim3(64,32),64,0,stream>>>(Qb,Kb,Vt,nullptr,att);

    if (!sph){
      k_gemm<1><<<dim3(8,16),256,0,stream>>>(att, wob, x, x, M_, 1024, 1024);
      k_rms<1><<<M_,256,0,stream>>>(x, h_bf);
      k_gemm<0><<<dim3(64,16),256,0,stream>>>(h_bf, wub, uvb, nullptr, M_, 8192, 1024);
      k_silu<0><<<8192,256,0,stream>>>(uvb, nullptr, gb);
      k_gemm<1><<<dim3(8,16),256,0,stream>>>(gb, wmb, x, x, M_, 1024, 4096);
    } else {
      k_gemm<2><<<dim3(8,16),256,0,stream>>>(att, wob, hf32, nullptr, M_, 1024, 1024);
      k_sphskip<<<M_,256,0,stream>>>(x, hf32, aal, x);
      k_rms<0><<<M_,256,0,stream>>>(x, h_bf);
      k_gemm<0><<<dim3(64,16),256,0,stream>>>(h_bf, wub, uvb, nullptr, M_, 8192, 1024);
      k_silu<1><<<8192,256,0,stream>>>(uvb, suv, gb);
      k_gemm<2><<<dim3(8,16),256,0,stream>>>(gb, wmb, hf32, nullptr, M_, 1024, 4096);
      k_sphskip<<<M_,256,0,stream>>>(x, hf32, mal, (float*)d_out);
    }
  }
}

// Round 5
// 1123.574 us; speedup vs baseline: 1.0346x; 1.0346x over previous
//
#include <hip/hip_runtime.h>
#include <stdint.h>
#include <stddef.h>

typedef __attribute__((ext_vector_type(8))) short short8;
typedef __attribute__((ext_vector_type(4))) float f32x4;
typedef unsigned short u16;
typedef unsigned int u32;

#define DEVI __device__ __forceinline__

static constexpr int T_ = 1024, C_ = 1024, M_ = 2048; // M = B*T

DEVI float bf2f(u16 u){ u32 x=((u32)u)<<16; float f; __builtin_memcpy(&f,&x,4); return f; }
DEVI u16 f2bf(float f){ u32 x; __builtin_memcpy(&x,&f,4); x += 0x7fffu + ((x>>16)&1u); return (u16)(x>>16); }

DEVI void gld_lds16(const u16* g, u16* l){
  __builtin_amdgcn_global_load_lds((const __attribute__((address_space(1))) void*)g,
                                   (__attribute__((address_space(3))) void*)l, 16, 0, 0);
}
DEVI f32x4 mfma16(short8 a, short8 b, f32x4 c){
  return __builtin_amdgcn_mfma_f32_16x16x32_bf16(a, b, c, 0, 0, 0);
}

// ---------------- cast f32 -> bf16 (4 elem / thread) ----------------
__global__ void k_cast(const float* __restrict__ in, u16* __restrict__ out){
  int i = (blockIdx.x*blockDim.x + threadIdx.x)*4;
  float4 v = *(const float4*)(in+i);
  uint2 o; o.x = (u32)f2bf(v.x) | ((u32)f2bf(v.y)<<16);
  o.y = (u32)f2bf(v.z) | ((u32)f2bf(v.w)<<16);
  *(uint2*)(out+i) = o;
}

// ---------------- rope tables ----------------
__global__ void k_tables(float* __restrict__ cosT, float* __restrict__ sinT){
  int i = blockIdx.x*256 + threadIdx.x;
  int t = i>>5, f = i&31;
  float inv = expf(-((float)f/32.f)*9.210340371976184f); // 10000^(-f/32)
  float fr = (float)t * inv;
  cosT[i] = cosf(fr); sinT[i] = sinf(fr);
}

// ---------------- rms (or plain cast) f32 -> bf16, row = 1024 ----------------
template<int NORM>
__global__ void k_rms(const float* __restrict__ x, u16* __restrict__ out){
  __shared__ float ps[4];
  int row = blockIdx.x, tid = threadIdx.x;
  float4 v = ((const float4*)(x + (size_t)row*C_))[tid];
  if (NORM){
    float ss = v.x*v.x+v.y*v.y+v.z*v.z+v.w*v.w;
    #pragma unroll
    for(int o=32;o>=1;o>>=1) ss += __shfl_xor(ss,o);
    if((tid&63)==0) ps[tid>>6]=ss;
    __syncthreads();
    ss = ps[0]+ps[1]+ps[2]+ps[3];
    float r = rsqrtf(ss*(1.f/C_) + 1e-6f);
    v.x*=r; v.y*=r; v.z*=r; v.w*=r;
  }
  uint2 o; o.x=(u32)f2bf(v.x)|((u32)f2bf(v.y)<<16);
  o.y=(u32)f2bf(v.z)|((u32)f2bf(v.w)<<16);
  ((uint2*)(out + (size_t)row*C_))[tid] = o;
}

// ---------------- GEMM: C[m,n] = sum_k A[m,k]*B[n,k]; A(MxK), B(NxK) bf16 ----------------
// EPI 0: bf16 out; 1: f32 out = Res + acc; 2: f32 out = acc
template<int EPI>
__global__ __launch_bounds__(256) void k_gemm(const u16* __restrict__ A, const u16* __restrict__ Bw,
    void* __restrict__ Cout, const float* __restrict__ Res, int M, int N, int K){
  __shared__ u16 As[128*32];
  __shared__ u16 Bs[128*32];
  const int tid = threadIdx.x, w = tid>>6, lane = tid&63;
  const int bm = blockIdx.y<<7, bn = blockIdx.x<<7;
  const int wr = w>>1, wc = w&1;
  const int sr = lane>>2, sc = lane&3;
  f32x4 acc[4][4] = {};
  const u16* ga0 = A  + (size_t)(bm + w*32 + sr)*K + sc*8;
  const u16* gb0 = Bw + (size_t)(bn + w*32 + sr)*K + sc*8;
  u16* la0 = &As[(w*32)*32];
  u16* lb0 = &Bs[(w*32)*32];
  const int r16 = lane&15, ko = (lane>>4)*8;
  for (int k0=0; k0<K; k0+=32){
    __syncthreads();
    gld_lds16(ga0 + k0, la0);
    gld_lds16(ga0 + (size_t)16*K + k0, la0 + 16*32);
    gld_lds16(gb0 + k0, lb0);
    gld_lds16(gb0 + (size_t)16*K + k0, lb0 + 16*32);
    __syncthreads();
    short8 af[4], bf[4];
    #pragma unroll
    for(int mf=0;mf<4;++mf) af[mf] = *(const short8*)&As[(wr*64+mf*16+r16)*32 + ko];
    #pragma unroll
    for(int nf=0;nf<4;++nf) bf[nf] = *(const short8*)&Bs[(wc*64+nf*16+r16)*32 + ko];
    #pragma unroll
    for(int mf=0;mf<4;++mf)
      #pragma unroll
      for(int nf=0;nf<4;++nf)
        acc[mf][nf] = mfma16(af[mf], bf[nf], acc[mf][nf]);
  }
  const int rr = (lane>>4)*4;
  #pragma unroll
  for(int mf=0;mf<4;++mf){
    #pragma unroll
    for(int nf=0;nf<4;++nf){
      #pragma unroll
      for(int r=0;r<4;++r){
        size_t idx = (size_t)(bm + wr*64 + mf*16 + rr + r)*N + (bn + wc*64 + nf*16 + r16);
        float val = acc[mf][nf][r];
        if (EPI==0)      ((u16*)Cout)[idx] = f2bf(val);
        else if (EPI==1) ((float*)Cout)[idx] = Res[idx] + val;
        else             ((float*)Cout)[idx] = val;
      }
    }
  }
}

// ---------------- rope on q,k (+ optional l2norm*sqk for sph); writes (BH,T,64) ----------------
template<int SPH>
__global__ void k_ropeqk(const u16* __restrict__ qkv, const float* __restrict__ cosT,
                         const float* __restrict__ sinT, const float* __restrict__ sqk,
                         u16* __restrict__ Qb, u16* __restrict__ Kb){
  int idx = blockIdx.x*4 + (threadIdx.x>>6);
  int lane = threadIdx.x&63;
  int bh = idx>>10, t = idx&1023;
  int b = bh>>4, h = bh&15;
  size_t qa = (size_t)(b*T_ + t)*3072 + h*64 + lane;
  float qv = bf2f(qkv[qa]), kv = bf2f(qkv[qa + 1024]);
  float c = cosT[t*32 + (lane&31)], s = sinT[t*32 + (lane&31)];
  float qo = __shfl(qv, lane^32), ko2 = __shfl(kv, lane^32);
  float qr = (lane<32) ? (qv*c + qo*s) : (qv*c - qo*s);
  float kr = (lane<32) ? (kv*c + ko2*s) : (kv*c - ko2*s);
  if (SPH){
    float sq = qr*qr, sk = kr*kr;
    #pragma unroll
    for(int o=32;o>=1;o>>=1){ sq += __shfl_xor(sq,o); sk += __shfl_xor(sk,o); }
    float sc2 = sqk[h*64+lane]*32.f;
    qr = qr / fmaxf(sqrtf(sq),1e-12f) * sc2;
    kr = kr / fmaxf(sqrtf(sk),1e-12f) * sc2;
  }
  size_t oa = (size_t)bh*T_*64 + (size_t)t*64 + lane;
  Qb[oa] = f2bf(qr); Kb[oa] = f2bf(kr);
}

// ---------------- V transpose: qkv v-part -> (BH, 64, T) ----------------
__global__ void k_vtrans(const u16* __restrict__ qkv, u16* __restrict__ Vt){
  __shared__ u16 tile[64][68];
  int bh = blockIdx.x, t0 = blockIdx.y*64;
  int b = bh>>4, h = bh&15;
  int tid = threadIdx.x;
  int tt = tid>>2, ch = tid&3;
  const u16* src = qkv + (size_t)(b*T_ + t0 + tt)*3072 + 2048 + h*64 + ch*16;
  short8 v0 = *(const short8*)src;
  short8 v1 = *(const short8*)(src+8);
  #pragma unroll
  for(int j=0;j<8;++j){ tile[tt][ch*16+j]=(u16)v0[j]; tile[tt][ch*16+8+j]=(u16)v1[j]; }
  __syncthreads();
  int d = tid>>2, tc = (tid&3)*16;
  short8 a, bb;
  #pragma unroll
  for(int j=0;j<8;++j){ a[j]=(short)tile[tc+j][d]; bb[j]=(short)tile[tc+8+j][d]; }
  u16* dst = Vt + ((size_t)bh*64 + d)*T_ + t0 + tc;
  *(short8*)dst = a; *(short8*)(dst+8) = bb;
}

// ---------------- split-K flash attention: each block does one 256-row K chunk ----------------
// partial O (un-normalized) + (m,l) go to workspace; k_attn_combine merges.
// GEOM: 0 euc, 1 hyp, 2 sph
template<int GEOM>
__global__ __launch_bounds__(64) void k_attn_split(const u16* __restrict__ Q, const u16* __restrict__ K,
    const u16* __restrict__ Vt, const float* __restrict__ khyp,
    float* __restrict__ partO, float* __restrict__ partML){
  int qt = blockIdx.x, bh = blockIdx.y, ch = blockIdx.z;
  int kend = qt*16 + 16;
  int kbeg = ch*256;
  if (kbeg >= kend) return;
  int klim = min(kbeg + 256, kend);
  __shared__ u16 P[16*32];
  int b = bh>>4, h = bh&15;
  int lane = threadIdx.x;
  int r16 = lane&15, g = lane>>4, ko = g*8;
  const u16* Qp = Q + (size_t)bh*T_*64;
  const u16* Kp = K + (size_t)bh*T_*64;
  const u16* Vp = Vt + (size_t)bh*64*T_;
  short8 qf0 = *(const short8*)&Qp[(size_t)(qt*16 + r16)*64 + ko];
  short8 qf1 = *(const short8*)&Qp[(size_t)(qt*16 + r16)*64 + 32 + ko];
  float kc=1.f, sqkc=1.f, tqr[4];
  if (GEOM==1){
    kc = khyp[h]; sqkc = sqrtf(kc);
    float ss=0;
    #pragma unroll
    for(int j=0;j<8;++j){ float a=bf2f((u16)qf0[j]); ss+=a*a; a=bf2f((u16)qf1[j]); ss+=a*a; }
    ss += __shfl_xor(ss,16); ss += __shfl_xor(ss,32);
    float tq = sqrtf(kc + ss);
    #pragma unroll
    for(int r=0;r<4;++r) tqr[r] = __shfl(tq, g*4+r);
  }
  f32x4 of[4] = {};
  float m[4], l[4];
  #pragma unroll
  for(int r=0;r<4;++r){ m[r]=-1e30f; l[r]=0.f; }
  int ntiles = (klim - kbeg + 31)>>5;
  for(int it=0; it<ntiles; ++it){
    int kt = kbeg + it*32;
    short8 kf00 = *(const short8*)&Kp[(size_t)(kt + r16)*64 + ko];
    short8 kf01 = *(const short8*)&Kp[(size_t)(kt + r16)*64 + 32 + ko];
    short8 kf10 = *(const short8*)&Kp[(size_t)(kt + 16 + r16)*64 + ko];
    short8 kf11 = *(const short8*)&Kp[(size_t)(kt + 16 + r16)*64 + 32 + ko];
    f32x4 s0={}, s1={};
    s0 = mfma16(qf0, kf00, s0); s0 = mfma16(qf1, kf01, s0);
    s1 = mfma16(qf0, kf10, s1); s1 = mfma16(qf1, kf11, s1);
    float tk0=0.f, tk1=0.f;
    if (GEOM==1){
      float ss0=0, ss1=0;
      #pragma unroll
      for(int j=0;j<8;++j){
        float a=bf2f((u16)kf00[j]); ss0+=a*a; a=bf2f((u16)kf01[j]); ss0+=a*a;
        a=bf2f((u16)kf10[j]); ss1+=a*a; a=bf2f((u16)kf11[j]); ss1+=a*a;
      }
      ss0 += __shfl_xor(ss0,16); ss0 += __shfl_xor(ss0,32);
      ss1 += __shfl_xor(ss1,16); ss1 += __shfl_xor(ss1,32);
      tk0 = sqrtf(kc+ss0); tk1 = sqrtf(kc+ss1);
    }
    float w0[4], w1[4];
    #pragma unroll
    for(int r=0;r<4;++r){
      int qg = qt*16 + g*4 + r;
      float a0, a1;
      if (GEOM==0){ a0 = s0[r]*(1.f/32.f); a1 = s1[r]*(1.f/32.f); }
      else if (GEOM==2){ a0 = s0[r]*32.f; a1 = s1[r]*32.f; }
      else {
        float z0 = (tqr[r]*tk0 - s0[r])/kc; z0 = fmaxf(z0, 1.f+1e-7f);
        float z1 = (tqr[r]*tk1 - s1[r])/kc; z1 = fmaxf(z1, 1.f+1e-7f);
        float d0 = sqkc * logf(z0 + sqrtf(z0*z0 - 1.f));
        float d1 = sqkc * logf(z1 + sqrtf(z1*z1 - 1.f));
        a0 = 1.f/(1e-6f + d0); a1 = 1.f/(1e-6f + d1);
      }
      if (kt + r16 > qg)      a0 = -1e30f;
      if (kt + 16 + r16 > qg) a1 = -1e30f;
      w0[r]=a0; w1[r]=a1;
    }
    #pragma unroll
    for(int r=0;r<4;++r){
      float mt = fmaxf(w0[r], w1[r]);
      #pragma unroll
      for(int o=1;o<16;o<<=1) mt = fmaxf(mt, __shfl_xor(mt,o));
      float mn = fmaxf(m[r], mt);
      float alpha = __expf(m[r]-mn);
      m[r]=mn;
      float p0 = __expf(w0[r]-mn), p1 = __expf(w1[r]-mn);
      float rs = p0+p1;
      #pragma unroll
      for(int o=1;o<16;o<<=1) rs += __shfl_xor(rs,o);
      l[r] = l[r]*alpha + rs;
      #pragma unroll
      for(int vb=0;vb<4;++vb) of[vb][r] *= alpha;
      P[(g*4+r)*32 + r16]      = f2bf(p0);
      P[(g*4+r)*32 + 16 + r16] = f2bf(p1);
    }
    __syncthreads();
    short8 pf = *(const short8*)&P[r16*32 + ko];
    #pragma unroll
    for(int vb=0;vb<4;++vb){
      short8 vf = *(const short8*)&Vp[(size_t)(vb*16 + r16)*T_ + kt + ko];
      of[vb] = mfma16(pf, vf, of[vb]);
    }
    __syncthreads();
  }
  size_t base = ((size_t)(bh*64 + qt)*4 + ch);
  float* po = partO + base*1024;
  #pragma unroll
  for(int vb=0;vb<4;++vb)
    #pragma unroll
    for(int r=0;r<4;++r)
      po[(g*4+r)*64 + vb*16 + r16] = of[vb][r];
  if (r16 == 0){
    #pragma unroll
    for(int r=0;r<4;++r){
      partML[(base*16 + g*4+r)*2    ] = m[r];
      partML[(base*16 + g*4+r)*2 + 1] = l[r];
    }
  }
}

// ---------------- combine split-K partials -> bf16 att (B,T,C layout) ----------------
__global__ __launch_bounds__(64) void k_attn_combine(const float* __restrict__ partO,
    const float* __restrict__ partML, u16* __restrict__ Oo){
  int qt = blockIdx.x, bh = blockIdx.y;
  int b = bh>>4, h = bh&15;
  int lane = threadIdx.x;
  int r16 = lane&15, g = lane>>4;
  int nch = (qt>>4) + 1;   // ceil((qt*16+16)/256)
  size_t base0 = ((size_t)(bh*64 + qt)*4);
  #pragma unroll
  for(int r=0;r<4;++r){
    int row = g*4 + r;
    float mstar = -1e30f;
    for(int c=0;c<nch;++c)
      mstar = fmaxf(mstar, partML[((base0+c)*16 + row)*2]);
    float lstar = 0.f;
    float ov[4] = {0.f,0.f,0.f,0.f};
    for(int c=0;c<nch;++c){
      float mc = partML[((base0+c)*16 + row)*2];
      float lc = partML[((base0+c)*16 + row)*2 + 1];
      float wgt = __expf(mc - mstar);
      lstar += lc * wgt;
      const float* po = partO + (base0+c)*1024 + row*64;
      #pragma unroll
      for(int vb=0;vb<4;++vb) ov[vb] += po[vb*16 + r16] * wgt;
    }
    float inv = 1.f / lstar;
    int t = qt*16 + row;
    #pragma unroll
    for(int vb=0;vb<4;++vb)
      Oo[((size_t)(b*T_ + t))*C_ + h*64 + vb*16 + r16] = f2bf(ov[vb] * inv);
  }
}

// ---------------- silu-mul (optionally * suv*32) bf16 ----------------
template<int SUV>
__global__ void k_silu(const u16* __restrict__ uv, const float* __restrict__ suv, u16* __restrict__ g){
  int i = blockIdx.x*256 + threadIdx.x;
  int m = i>>10, j = (i&1023)*4;
  const u16* up = uv + (size_t)m*8192 + j;
  uint2 uu = *(const uint2*)up;
  uint2 vv = *(const uint2*)(up+4096);
  float u[4] = { bf2f((u16)(uu.x&0xffff)), bf2f((u16)(uu.x>>16)), bf2f((u16)(uu.y&0xffff)), bf2f((u16)(uu.y>>16)) };
  float v[4] = { bf2f((u16)(vv.x&0xffff)), bf2f((u16)(vv.x>>16)), bf2f((u16)(vv.y&0xffff)), bf2f((u16)(vv.y>>16)) };
  float o[4];
  #pragma unroll
  for(int e=0;e<4;++e){
    float ue=u[e], ve=v[e];
    if (SUV){ ue *= suv[j+e]*32.0f; ve *= suv[4096+j+e]*32.0f; }
    o[e] = ue * (ve / (1.0f + __expf(-ve)));
  }
  uint2 oo; oo.x=(u32)f2bf(o[0])|((u32)f2bf(o[1])<<16); oo.y=(u32)f2bf(o[2])|((u32)f2bf(o[3])<<16);
  *(uint2*)(g + (size_t)m*4096 + j) = oo;
}

// ---------------- spherical skip: out = l2n(l2n(x) + lr*(l2n(h)-l2n(x))) ----------------
__global__ void k_sphskip(const float* __restrict__ x, const float* __restrict__ hh,
                          const float* __restrict__ alpha, float* __restrict__ out){
  __shared__ float red[3][4];
  int row = blockIdx.x, tid = threadIdx.x;
  float4 xv = ((const float4*)(x  + (size_t)row*C_))[tid];
  float4 hv = ((const float4*)(hh + (size_t)row*C_))[tid];
  float ssx = xv.x*xv.x+xv.y*xv.y+xv.z*xv.z+xv.w*xv.w;
  float ssh = hv.x*hv.x+hv.y*hv.y+hv.z*hv.z+hv.w*hv.w;
  #pragma unroll
  for(int o=32;o>=1;o>>=1){ ssx += __shfl_xor(ssx,o); ssh += __shfl_xor(ssh,o); }
  if((tid&63)==0){ red[0][tid>>6]=ssx; red[1][tid>>6]=ssh; }
  __syncthreads();
  ssx = red[0][0]+red[0][1]+red[0][2]+red[0][3];
  ssh = red[1][0]+red[1][1]+red[1][2]+red[1][3];
  float rx = 1.f/fmaxf(sqrtf(ssx),1e-12f), rh = 1.f/fmaxf(sqrtf(ssh),1e-12f);
  float4 al = ((const float4*)alpha)[tid];
  float y[4]; float ssy=0.f;
  { float a0=xv.x*rx, b0=hv.x*rh, lr=fabsf(al.x*1.6f); y[0]=a0+lr*(b0-a0); ssy+=y[0]*y[0]; }
  { float a0=xv.y*rx, b0=hv.y*rh, lr=fabsf(al.y*1.6f); y[1]=a0+lr*(b0-a0); ssy+=y[1]*y[1]; }
  { float a0=xv.z*rx, b0=hv.z*rh, lr=fabsf(al.z*1.6f); y[2]=a0+lr*(b0-a0); ssy+=y[2]*y[2]; }
  { float a0=xv.w*rx, b0=hv.w*rh, lr=fabsf(al.w*1.6f); y[3]=a0+lr*(b0-a0); ssy+=y[3]*y[3]; }
  #pragma unroll
  for(int o=32;o>=1;o>>=1) ssy += __shfl_xor(ssy,o);
  if((tid&63)==0) red[2][tid>>6]=ssy;
  __syncthreads();
  ssy = red[2][0]+red[2][1]+red[2][2]+red[2][3];
  float ry = 1.f/fmaxf(sqrtf(ssy),1e-12f);
  float4 o4; o4.x=y[0]*ry; o4.y=y[1]*ry; o4.z=y[2]*ry; o4.w=y[3]*ry;
  ((float4*)(out + (size_t)row*C_))[tid] = o4;
}

extern "C" void kernel_launch(void* const* d_in, const int* in_sizes, int n_in,
                              void* d_out, int out_size, void* d_ws, size_t ws_size,
                              hipStream_t stream){
  (void)n_in; (void)out_size; (void)ws_size;
  int i_khyp, sphb;
  if (in_sizes[9]==16){ i_khyp=9; sphb=10; } else { i_khyp=13; sphb=9; }
  const float* Wq[3] = {(const float*)d_in[1], (const float*)d_in[5], (const float*)d_in[sphb+0]};
  const float* Wo[3] = {(const float*)d_in[2], (const float*)d_in[6], (const float*)d_in[sphb+1]};
  const float* Wu[3] = {(const float*)d_in[3], (const float*)d_in[7], (const float*)d_in[sphb+2]};
  const float* Wm[3] = {(const float*)d_in[4], (const float*)d_in[8], (const float*)d_in[sphb+3]};
  const float* khyp = (const float*)d_in[i_khyp];
  const float* sqk  = (const float*)d_in[14];
  const float* suv  = (const float*)d_in[15];
  const float* aal  = (const float*)d_in[16];
  const float* mal  = (const float*)d_in[17];

  char* p = (char*)d_ws;
  auto alloc = [&](size_t bytes)->char*{ char* r=p; p += (bytes+255)&~(size_t)255; return r; };
  float* x    = (float*)alloc((size_t)M_*C_*4);
  float* hf32 = (float*)alloc((size_t)M_*C_*4);
  u16* h_bf   = (u16*)alloc((size_t)M_*C_*2);
  u16* qkv    = (u16*)alloc((size_t)M_*3072*2);
  u16* Qb     = (u16*)alloc((size_t)M_*1024*2);
  u16* Kb     = (u16*)alloc((size_t)M_*1024*2);
  u16* Vt     = (u16*)alloc((size_t)M_*1024*2);
  u16* att    = (u16*)alloc((size_t)M_*1024*2);
  u16* uvb    = (u16*)alloc((size_t)M_*8192*2);
  u16* gb     = (u16*)alloc((size_t)M_*4096*2);
  u16* wqb    = (u16*)alloc((size_t)3*C_*C_*2);
  u16* wob    = (u16*)alloc((size_t)C_*C_*2);
  u16* wub    = (u16*)alloc((size_t)8*C_*C_*2);
  u16* wmb    = (u16*)alloc((size_t)4*C_*C_*2);
  float* cosT = (float*)alloc((size_t)T_*32*4);
  float* sinT = (float*)alloc((size_t)T_*32*4);
  // split-K attention partials: ALIASED onto uvb+gb (48 MB). Safe by stream
  // order: attn+combine finish before uvb/gb are written in the MLP phase,
  // and next geometry's attn runs after this geometry's MLP reads gb.
  float* partO  = (float*)uvb;                       // 2048*4*1024 f32 = 33.6 MB
  float* partML = partO + (size_t)8*1024*1024;       // 1 MB, lands in gb region

  hipMemcpyAsync(x, d_in[0], (size_t)M_*C_*4, hipMemcpyDeviceToDevice, stream);
  k_tables<<<T_*32/256, 256, 0, stream>>>(cosT, sinT);

  for (int gi=0; gi<3; ++gi){
    bool sph = (gi==2);
    k_cast<<<3*C_*C_/1024, 256, 0, stream>>>(Wq[gi], wqb);
    k_cast<<<  C_*C_/1024, 256, 0, stream>>>(Wo[gi], wob);
    k_cast<<<8*C_*C_/1024, 256, 0, stream>>>(Wu[gi], wub);
    k_cast<<<4*C_*C_/1024, 256, 0, stream>>>(Wm[gi], wmb);

    if (!sph) k_rms<1><<<M_,256,0,stream>>>(x, h_bf);
    else      k_rms<0><<<M_,256,0,stream>>>(x, h_bf);
    k_gemm<0><<<dim3(24,16),256,0,stream>>>(h_bf, wqb, qkv, nullptr, M_, 3072, 1024);
    if (sph) k_ropeqk<1><<<8192,256,0,stream>>>(qkv, cosT, sinT, sqk, Qb, Kb);
    else     k_ropeqk<0><<<8192,256,0,stream>>>(qkv, cosT, sinT, nullptr, Qb, Kb);
    k_vtrans<<<dim3(32,16),256,0,stream>>>(qkv, Vt);
    if (gi==0)      k_attn_split<0><<<dim3(64,32,4),64,0,stream>>>(Qb,Kb,Vt,nullptr,partO,partML);
    else if (gi==1) k_attn_split<1><<<dim3(64,32,4),64,0,stream>>>(Qb,Kb,Vt,khyp,partO,partML);
    else            k_attn_split<2><<<dim3(64,32,4),64,0,stream>>>(Qb,Kb,Vt,nullptr,partO,partML);
    k_attn_combine<<<dim3(64,32),64,0,stream>>>(partO, partML, att);

    if (!sph){
      k_gemm<1><<<dim3(8,16),256,0,stream>>>(att, wob, x, x, M_, 1024, 1024);
      k_rms<1><<<M_,256,0,stream>>>(x, h_bf);
      k_gemm<0><<<dim3(64,16),256,0,stream>>>(h_bf, wub, uvb, nullptr, M_, 8192, 1024);
      k_silu<0><<<8192,256,0,stream>>>(uvb, nullptr, gb);
      k_gemm<1><<<dim3(8,16),256,0,stream>>>(gb, wmb, x, x, M_, 1024, 4096);
    } else {
      k_gemm<2><<<dim3(8,16),256,0,stream>>>(att, wob, hf32, nullptr, M_, 1024, 1024);
      k_sphskip<<<M_,256,0,stream>>>(x, hf32, aal, x);
      k_rms<0><<<M_,256,0,stream>>>(x, h_bf);
      k_gemm<0><<<dim3(64,16),256,0,stream>>>(h_bf, wub, uvb, nullptr, M_, 8192, 1024);
      k_silu<1><<<8192,256,0,stream>>>(uvb, suv, gb);
      k_gemm<2><<<dim3(8,16),256,0,stream>>>(gb, wmb, hf32, nullptr, M_, 1024, 4096);
      k_sphskip<<<M_,256,0,stream>>>(x, hf32, mal, (float*)d_out);
    }
  }
}

// Round 6
// 960.822 us; speedup vs baseline: 1.2099x; 1.1694x over previous
//
#include <hip/hip_runtime.h>
#include <stdint.h>
#include <stddef.h>

typedef __attribute__((ext_vector_type(8))) short short8;
typedef __attribute__((ext_vector_type(4))) float f32x4;
typedef unsigned short u16;
typedef unsigned int u32;

#define DEVI __device__ __forceinline__

static constexpr int T_ = 1024, C_ = 1024, M_ = 2048; // M = B*T

DEVI float bf2f(u16 u){ u32 x=((u32)u)<<16; float f; __builtin_memcpy(&f,&x,4); return f; }
DEVI u16 f2bf(float f){ u32 x; __builtin_memcpy(&x,&f,4); x += 0x7fffu + ((x>>16)&1u); return (u16)(x>>16); }

DEVI void gld_lds16(const u16* g, u16* l){
  __builtin_amdgcn_global_load_lds((const __attribute__((address_space(1))) void*)g,
                                   (__attribute__((address_space(3))) void*)l, 16, 0, 0);
}
DEVI f32x4 mfma16(short8 a, short8 b, f32x4 c){
  return __builtin_amdgcn_mfma_f32_16x16x32_bf16(a, b, c, 0, 0, 0);
}

// ---------------- fused cast of all 4 weights f32 -> bf16 ----------------
// block coverage (units of 1024 elems): Wq 3072 | Wo 1024 | Wu 8192 | Wm 4096
__global__ void k_cast4(const float* __restrict__ q, const float* __restrict__ o,
                        const float* __restrict__ u, const float* __restrict__ m,
                        u16* __restrict__ qo, u16* __restrict__ oo,
                        u16* __restrict__ uo, u16* __restrict__ mo){
  int blk = blockIdx.x;
  const float* src; u16* dst; int base;
  if (blk < 3072)      { src=q; dst=qo; base=blk; }
  else if (blk < 4096) { src=o; dst=oo; base=blk-3072; }
  else if (blk < 12288){ src=u; dst=uo; base=blk-4096; }
  else                 { src=m; dst=mo; base=blk-12288; }
  size_t i = (size_t)base*1024 + threadIdx.x*4;
  float4 v = *(const float4*)(src+i);
  uint2 ov; ov.x = (u32)f2bf(v.x) | ((u32)f2bf(v.y)<<16);
  ov.y = (u32)f2bf(v.z) | ((u32)f2bf(v.w)<<16);
  *(uint2*)(dst+i) = ov;
}

// ---------------- rope tables ----------------
__global__ void k_tables(float* __restrict__ cosT, float* __restrict__ sinT){
  int i = blockIdx.x*256 + threadIdx.x;
  int t = i>>5, f = i&31;
  float inv = expf(-((float)f/32.f)*9.210340371976184f); // 10000^(-f/32)
  float fr = (float)t * inv;
  cosT[i] = cosf(fr); sinT[i] = sinf(fr);
}

// ---------------- rms (or plain cast) f32 -> bf16, row = 1024 ----------------
template<int NORM>
__global__ void k_rms(const float* __restrict__ x, u16* __restrict__ out){
  __shared__ float ps[4];
  int row = blockIdx.x, tid = threadIdx.x;
  float4 v = ((const float4*)(x + (size_t)row*C_))[tid];
  if (NORM){
    float ss = v.x*v.x+v.y*v.y+v.z*v.z+v.w*v.w;
    #pragma unroll
    for(int o=32;o>=1;o>>=1) ss += __shfl_xor(ss,o);
    if((tid&63)==0) ps[tid>>6]=ss;
    __syncthreads();
    ss = ps[0]+ps[1]+ps[2]+ps[3];
    float r = rsqrtf(ss*(1.f/C_) + 1e-6f);
    v.x*=r; v.y*=r; v.z*=r; v.w*=r;
  }
  uint2 o; o.x=(u32)f2bf(v.x)|((u32)f2bf(v.y)<<16);
  o.y=(u32)f2bf(v.z)|((u32)f2bf(v.w)<<16);
  ((uint2*)(out + (size_t)row*C_))[tid] = o;
}

// ---------------- GEMM: C[m,n] = sum_k A[m,k]*B[n,k]; A(MxK), B(NxK) bf16 ----------------
// EPI 0: bf16 out; 1: f32 out = Res + acc; 2: f32 out = acc
template<int EPI>
__global__ __launch_bounds__(256) void k_gemm(const u16* __restrict__ A, const u16* __restrict__ Bw,
    void* __restrict__ Cout, const float* __restrict__ Res, int M, int N, int K){
  __shared__ u16 As[128*32];
  __shared__ u16 Bs[128*32];
  const int tid = threadIdx.x, w = tid>>6, lane = tid&63;
  const int bm = blockIdx.y<<7, bn = blockIdx.x<<7;
  const int wr = w>>1, wc = w&1;
  const int sr = lane>>2, sc = lane&3;
  f32x4 acc[4][4] = {};
  const u16* ga0 = A  + (size_t)(bm + w*32 + sr)*K + sc*8;
  const u16* gb0 = Bw + (size_t)(bn + w*32 + sr)*K + sc*8;
  u16* la0 = &As[(w*32)*32];
  u16* lb0 = &Bs[(w*32)*32];
  const int r16 = lane&15, ko = (lane>>4)*8;
  for (int k0=0; k0<K; k0+=32){
    __syncthreads();
    gld_lds16(ga0 + k0, la0);
    gld_lds16(ga0 + (size_t)16*K + k0, la0 + 16*32);
    gld_lds16(gb0 + k0, lb0);
    gld_lds16(gb0 + (size_t)16*K + k0, lb0 + 16*32);
    __syncthreads();
    short8 af[4], bf[4];
    #pragma unroll
    for(int mf=0;mf<4;++mf) af[mf] = *(const short8*)&As[(wr*64+mf*16+r16)*32 + ko];
    #pragma unroll
    for(int nf=0;nf<4;++nf) bf[nf] = *(const short8*)&Bs[(wc*64+nf*16+r16)*32 + ko];
    #pragma unroll
    for(int mf=0;mf<4;++mf)
      #pragma unroll
      for(int nf=0;nf<4;++nf)
        acc[mf][nf] = mfma16(af[mf], bf[nf], acc[mf][nf]);
  }
  const int rr = (lane>>4)*4;
  #pragma unroll
  for(int mf=0;mf<4;++mf){
    #pragma unroll
    for(int nf=0;nf<4;++nf){
      #pragma unroll
      for(int r=0;r<4;++r){
        size_t idx = (size_t)(bm + wr*64 + mf*16 + rr + r)*N + (bn + wc*64 + nf*16 + r16);
        float val = acc[mf][nf][r];
        if (EPI==0)      ((u16*)Cout)[idx] = f2bf(val);
        else if (EPI==1) ((float*)Cout)[idx] = Res[idx] + val;
        else             ((float*)Cout)[idx] = val;
      }
    }
  }
}

// ---------------- split-K GEMM: partial f32 C per z-chunk ----------------
__global__ __launch_bounds__(256) void k_gemm_sk(const u16* __restrict__ A, const u16* __restrict__ Bw,
    float* __restrict__ partC, int M, int N, int K, int KC){
  __shared__ u16 As[128*32];
  __shared__ u16 Bs[128*32];
  const int tid = threadIdx.x, w = tid>>6, lane = tid&63;
  const int bm = blockIdx.y<<7, bn = blockIdx.x<<7;
  const int kb = blockIdx.z*KC;
  const int wr = w>>1, wc = w&1;
  const int sr = lane>>2, sc = lane&3;
  f32x4 acc[4][4] = {};
  const u16* ga0 = A  + (size_t)(bm + w*32 + sr)*K + sc*8;
  const u16* gb0 = Bw + (size_t)(bn + w*32 + sr)*K + sc*8;
  u16* la0 = &As[(w*32)*32];
  u16* lb0 = &Bs[(w*32)*32];
  const int r16 = lane&15, ko = (lane>>4)*8;
  for (int k0=kb; k0<kb+KC; k0+=32){
    __syncthreads();
    gld_lds16(ga0 + k0, la0);
    gld_lds16(ga0 + (size_t)16*K + k0, la0 + 16*32);
    gld_lds16(gb0 + k0, lb0);
    gld_lds16(gb0 + (size_t)16*K + k0, lb0 + 16*32);
    __syncthreads();
    short8 af[4], bf[4];
    #pragma unroll
    for(int mf=0;mf<4;++mf) af[mf] = *(const short8*)&As[(wr*64+mf*16+r16)*32 + ko];
    #pragma unroll
    for(int nf=0;nf<4;++nf) bf[nf] = *(const short8*)&Bs[(wc*64+nf*16+r16)*32 + ko];
    #pragma unroll
    for(int mf=0;mf<4;++mf)
      #pragma unroll
      for(int nf=0;nf<4;++nf)
        acc[mf][nf] = mfma16(af[mf], bf[nf], acc[mf][nf]);
  }
  float* pc = partC + (size_t)blockIdx.z*M*N;
  const int rr = (lane>>4)*4;
  #pragma unroll
  for(int mf=0;mf<4;++mf)
    #pragma unroll
    for(int nf=0;nf<4;++nf)
      #pragma unroll
      for(int r=0;r<4;++r){
        size_t idx = (size_t)(bm + wr*64 + mf*16 + rr + r)*N + (bn + wc*64 + nf*16 + r16);
        pc[idx] = acc[mf][nf][r];
      }
}

// ---------------- split-K reduce: out = (RES? Res : 0) + sum_z partC[z] ----------------
template<int RES, int NS>
__global__ void k_skred(const float* __restrict__ partC, const float* __restrict__ Res,
                        float* __restrict__ out, int MN){
  int i = (blockIdx.x*256 + threadIdx.x)*4;
  float4 s = *(const float4*)(partC + i);
  #pragma unroll
  for(int z=1; z<NS; ++z){
    float4 t = *(const float4*)(partC + (size_t)z*MN + i);
    s.x+=t.x; s.y+=t.y; s.z+=t.z; s.w+=t.w;
  }
  if (RES){
    float4 rv = *(const float4*)(Res + i);
    s.x+=rv.x; s.y+=rv.y; s.z+=rv.z; s.w+=rv.w;
  }
  *(float4*)(out + i) = s;
}

// ---------------- rope on q,k (+ optional l2norm*sqk for sph); writes (BH,T,64) ----------------
template<int SPH>
__global__ void k_ropeqk(const u16* __restrict__ qkv, const float* __restrict__ cosT,
                         const float* __restrict__ sinT, const float* __restrict__ sqk,
                         u16* __restrict__ Qb, u16* __restrict__ Kb){
  int idx = blockIdx.x*4 + (threadIdx.x>>6);
  int lane = threadIdx.x&63;
  int bh = idx>>10, t = idx&1023;
  int b = bh>>4, h = bh&15;
  size_t qa = (size_t)(b*T_ + t)*3072 + h*64 + lane;
  float qv = bf2f(qkv[qa]), kv = bf2f(qkv[qa + 1024]);
  float c = cosT[t*32 + (lane&31)], s = sinT[t*32 + (lane&31)];
  float qo = __shfl(qv, lane^32), ko2 = __shfl(kv, lane^32);
  float qr = (lane<32) ? (qv*c + qo*s) : (qv*c - qo*s);
  float kr = (lane<32) ? (kv*c + ko2*s) : (kv*c - ko2*s);
  if (SPH){
    float sq = qr*qr, sk = kr*kr;
    #pragma unroll
    for(int o=32;o>=1;o>>=1){ sq += __shfl_xor(sq,o); sk += __shfl_xor(sk,o); }
    float sc2 = sqk[h*64+lane]*32.f;
    qr = qr / fmaxf(sqrtf(sq),1e-12f) * sc2;
    kr = kr / fmaxf(sqrtf(sk),1e-12f) * sc2;
  }
  size_t oa = (size_t)bh*T_*64 + (size_t)t*64 + lane;
  Qb[oa] = f2bf(qr); Kb[oa] = f2bf(kr);
}

// ---------------- V transpose: qkv v-part -> (BH, 64, T) ----------------
__global__ void k_vtrans(const u16* __restrict__ qkv, u16* __restrict__ Vt){
  __shared__ u16 tile[64][68];
  int bh = blockIdx.x, t0 = blockIdx.y*64;
  int b = bh>>4, h = bh&15;
  int tid = threadIdx.x;
  int tt = tid>>2, ch = tid&3;
  const u16* src = qkv + (size_t)(b*T_ + t0 + tt)*3072 + 2048 + h*64 + ch*16;
  short8 v0 = *(const short8*)src;
  short8 v1 = *(const short8*)(src+8);
  #pragma unroll
  for(int j=0;j<8;++j){ tile[tt][ch*16+j]=(u16)v0[j]; tile[tt][ch*16+8+j]=(u16)v1[j]; }
  __syncthreads();
  int d = tid>>2, tc = (tid&3)*16;
  short8 a, bb;
  #pragma unroll
  for(int j=0;j<8;++j){ a[j]=(short)tile[tc+j][d]; bb[j]=(short)tile[tc+8+j][d]; }
  u16* dst = Vt + ((size_t)bh*64 + d)*T_ + t0 + tc;
  *(short8*)dst = a; *(short8*)(dst+8) = bb;
}

// ---------------- split-K flash attention: each block does one 256-row K chunk ----------------
template<int GEOM>
__global__ __launch_bounds__(64) void k_attn_split(const u16* __restrict__ Q, const u16* __restrict__ K,
    const u16* __restrict__ Vt, const float* __restrict__ khyp,
    float* __restrict__ partO, float* __restrict__ partML){
  int qt = blockIdx.x, bh = blockIdx.y, ch = blockIdx.z;
  int kend = qt*16 + 16;
  int kbeg = ch*256;
  if (kbeg >= kend) return;
  int klim = min(kbeg + 256, kend);
  __shared__ u16 P[16*32];
  int b = bh>>4, h = bh&15;
  int lane = threadIdx.x;
  int r16 = lane&15, g = lane>>4, ko = g*8;
  const u16* Qp = Q + (size_t)bh*T_*64;
  const u16* Kp = K + (size_t)bh*T_*64;
  const u16* Vp = Vt + (size_t)bh*64*T_;
  short8 qf0 = *(const short8*)&Qp[(size_t)(qt*16 + r16)*64 + ko];
  short8 qf1 = *(const short8*)&Qp[(size_t)(qt*16 + r16)*64 + 32 + ko];
  float kc=1.f, sqkc=1.f, tqr[4];
  if (GEOM==1){
    kc = khyp[h]; sqkc = sqrtf(kc);
    float ss=0;
    #pragma unroll
    for(int j=0;j<8;++j){ float a=bf2f((u16)qf0[j]); ss+=a*a; a=bf2f((u16)qf1[j]); ss+=a*a; }
    ss += __shfl_xor(ss,16); ss += __shfl_xor(ss,32);
    float tq = sqrtf(kc + ss);
    #pragma unroll
    for(int r=0;r<4;++r) tqr[r] = __shfl(tq, g*4+r);
  }
  f32x4 of[4] = {};
  float m[4], l[4];
  #pragma unroll
  for(int r=0;r<4;++r){ m[r]=-1e30f; l[r]=0.f; }
  int ntiles = (klim - kbeg + 31)>>5;
  for(int it=0; it<ntiles; ++it){
    int kt = kbeg + it*32;
    short8 kf00 = *(const short8*)&Kp[(size_t)(kt + r16)*64 + ko];
    short8 kf01 = *(const short8*)&Kp[(size_t)(kt + r16)*64 + 32 + ko];
    short8 kf10 = *(const short8*)&Kp[(size_t)(kt + 16 + r16)*64 + ko];
    short8 kf11 = *(const short8*)&Kp[(size_t)(kt + 16 + r16)*64 + 32 + ko];
    f32x4 s0={}, s1={};
    s0 = mfma16(qf0, kf00, s0); s0 = mfma16(qf1, kf01, s0);
    s1 = mfma16(qf0, kf10, s1); s1 = mfma16(qf1, kf11, s1);
    float tk0=0.f, tk1=0.f;
    if (GEOM==1){
      float ss0=0, ss1=0;
      #pragma unroll
      for(int j=0;j<8;++j){
        float a=bf2f((u16)kf00[j]); ss0+=a*a; a=bf2f((u16)kf01[j]); ss0+=a*a;
        a=bf2f((u16)kf10[j]); ss1+=a*a; a=bf2f((u16)kf11[j]); ss1+=a*a;
      }
      ss0 += __shfl_xor(ss0,16); ss0 += __shfl_xor(ss0,32);
      ss1 += __shfl_xor(ss1,16); ss1 += __shfl_xor(ss1,32);
      tk0 = sqrtf(kc+ss0); tk1 = sqrtf(kc+ss1);
    }
    float w0[4], w1[4];
    #pragma unroll
    for(int r=0;r<4;++r){
      int qg = qt*16 + g*4 + r;
      float a0, a1;
      if (GEOM==0){ a0 = s0[r]*(1.f/32.f); a1 = s1[r]*(1.f/32.f); }
      else if (GEOM==2){ a0 = s0[r]*32.f; a1 = s1[r]*32.f; }
      else {
        float z0 = (tqr[r]*tk0 - s0[r])/kc; z0 = fmaxf(z0, 1.f+1e-7f);
        float z1 = (tqr[r]*tk1 - s1[r])/kc; z1 = fmaxf(z1, 1.f+1e-7f);
        float d0 = sqkc * logf(z0 + sqrtf(z0*z0 - 1.f));
        float d1 = sqkc * logf(z1 + sqrtf(z1*z1 - 1.f));
        a0 = 1.f/(1e-6f + d0); a1 = 1.f/(1e-6f + d1);
      }
      if (kt + r16 > qg)      a0 = -1e30f;
      if (kt + 16 + r16 > qg) a1 = -1e30f;
      w0[r]=a0; w1[r]=a1;
    }
    #pragma unroll
    for(int r=0;r<4;++r){
      float mt = fmaxf(w0[r], w1[r]);
      #pragma unroll
      for(int o=1;o<16;o<<=1) mt = fmaxf(mt, __shfl_xor(mt,o));
      float mn = fmaxf(m[r], mt);
      float alpha = __expf(m[r]-mn);
      m[r]=mn;
      float p0 = __expf(w0[r]-mn), p1 = __expf(w1[r]-mn);
      float rs = p0+p1;
      #pragma unroll
      for(int o=1;o<16;o<<=1) rs += __shfl_xor(rs,o);
      l[r] = l[r]*alpha + rs;
      #pragma unroll
      for(int vb=0;vb<4;++vb) of[vb][r] *= alpha;
      P[(g*4+r)*32 + r16]      = f2bf(p0);
      P[(g*4+r)*32 + 16 + r16] = f2bf(p1);
    }
    __syncthreads();
    short8 pf = *(const short8*)&P[r16*32 + ko];
    #pragma unroll
    for(int vb=0;vb<4;++vb){
      short8 vf = *(const short8*)&Vp[(size_t)(vb*16 + r16)*T_ + kt + ko];
      of[vb] = mfma16(pf, vf, of[vb]);
    }
    __syncthreads();
  }
  size_t base = ((size_t)(bh*64 + qt)*4 + ch);
  float* po = partO + base*1024;
  #pragma unroll
  for(int vb=0;vb<4;++vb)
    #pragma unroll
    for(int r=0;r<4;++r)
      po[(g*4+r)*64 + vb*16 + r16] = of[vb][r];
  if (r16 == 0){
    #pragma unroll
    for(int r=0;r<4;++r){
      partML[(base*16 + g*4+r)*2    ] = m[r];
      partML[(base*16 + g*4+r)*2 + 1] = l[r];
    }
  }
}

// ---------------- combine split-K partials -> bf16 att (B,T,C layout) ----------------
__global__ __launch_bounds__(64) void k_attn_combine(const float* __restrict__ partO,
    const float* __restrict__ partML, u16* __restrict__ Oo){
  int qt = blockIdx.x, bh = blockIdx.y;
  int b = bh>>4, h = bh&15;
  int lane = threadIdx.x;
  int r16 = lane&15, g = lane>>4;
  int nch = (qt>>4) + 1;   // ceil((qt*16+16)/256)
  size_t base0 = ((size_t)(bh*64 + qt)*4);
  #pragma unroll
  for(int r=0;r<4;++r){
    int row = g*4 + r;
    float mstar = -1e30f;
    for(int c=0;c<nch;++c)
      mstar = fmaxf(mstar, partML[((base0+c)*16 + row)*2]);
    float lstar = 0.f;
    float ov[4] = {0.f,0.f,0.f,0.f};
    for(int c=0;c<nch;++c){
      float mc = partML[((base0+c)*16 + row)*2];
      float lc = partML[((base0+c)*16 + row)*2 + 1];
      float wgt = __expf(mc - mstar);
      lstar += lc * wgt;
      const float* po = partO + (base0+c)*1024 + row*64;
      #pragma unroll
      for(int vb=0;vb<4;++vb) ov[vb] += po[vb*16 + r16] * wgt;
    }
    float inv = 1.f / lstar;
    int t = qt*16 + row;
    #pragma unroll
    for(int vb=0;vb<4;++vb)
      Oo[((size_t)(b*T_ + t))*C_ + h*64 + vb*16 + r16] = f2bf(ov[vb] * inv);
  }
}

// ---------------- silu-mul (optionally * suv*32) bf16 ----------------
template<int SUV>
__global__ void k_silu(const u16* __restrict__ uv, const float* __restrict__ suv, u16* __restrict__ g){
  int i = blockIdx.x*256 + threadIdx.x;
  int m = i>>10, j = (i&1023)*4;
  const u16* up = uv + (size_t)m*8192 + j;
  uint2 uu = *(const uint2*)up;
  uint2 vv = *(const uint2*)(up+4096);
  float u[4] = { bf2f((u16)(uu.x&0xffff)), bf2f((u16)(uu.x>>16)), bf2f((u16)(uu.y&0xffff)), bf2f((u16)(uu.y>>16)) };
  float v[4] = { bf2f((u16)(vv.x&0xffff)), bf2f((u16)(vv.x>>16)), bf2f((u16)(vv.y&0xffff)), bf2f((u16)(vv.y>>16)) };
  float o[4];
  #pragma unroll
  for(int e=0;e<4;++e){
    float ue=u[e], ve=v[e];
    if (SUV){ ue *= suv[j+e]*32.0f; ve *= suv[4096+j+e]*32.0f; }
    o[e] = ue * (ve / (1.0f + __expf(-ve)));
  }
  uint2 oo; oo.x=(u32)f2bf(o[0])|((u32)f2bf(o[1])<<16); oo.y=(u32)f2bf(o[2])|((u32)f2bf(o[3])<<16);
  *(uint2*)(g + (size_t)m*4096 + j) = oo;
}

// ---------------- spherical skip: out = l2n(l2n(x) + lr*(l2n(h)-l2n(x))) ----------------
__global__ void k_sphskip(const float* __restrict__ x, const float* __restrict__ hh,
                          const float* __restrict__ alpha, float* __restrict__ out){
  __shared__ float red[3][4];
  int row = blockIdx.x, tid = threadIdx.x;
  float4 xv = ((const float4*)(x  + (size_t)row*C_))[tid];
  float4 hv = ((const float4*)(hh + (size_t)row*C_))[tid];
  float ssx = xv.x*xv.x+xv.y*xv.y+xv.z*xv.z+xv.w*xv.w;
  float ssh = hv.x*hv.x+hv.y*hv.y+hv.z*hv.z+hv.w*hv.w;
  #pragma unroll
  for(int o=32;o>=1;o>>=1){ ssx += __shfl_xor(ssx,o); ssh += __shfl_xor(ssh,o); }
  if((tid&63)==0){ red[0][tid>>6]=ssx; red[1][tid>>6]=ssh; }
  __syncthreads();
  ssx = red[0][0]+red[0][1]+red[0][2]+red[0][3];
  ssh = red[1][0]+red[1][1]+red[1][2]+red[1][3];
  float rx = 1.f/fmaxf(sqrtf(ssx),1e-12f), rh = 1.f/fmaxf(sqrtf(ssh),1e-12f);
  float4 al = ((const float4*)alpha)[tid];
  float y[4]; float ssy=0.f;
  { float a0=xv.x*rx, b0=hv.x*rh, lr=fabsf(al.x*1.6f); y[0]=a0+lr*(b0-a0); ssy+=y[0]*y[0]; }
  { float a0=xv.y*rx, b0=hv.y*rh, lr=fabsf(al.y*1.6f); y[1]=a0+lr*(b0-a0); ssy+=y[1]*y[1]; }
  { float a0=xv.z*rx, b0=hv.z*rh, lr=fabsf(al.z*1.6f); y[2]=a0+lr*(b0-a0); ssy+=y[2]*y[2]; }
  { float a0=xv.w*rx, b0=hv.w*rh, lr=fabsf(al.w*1.6f); y[3]=a0+lr*(b0-a0); ssy+=y[3]*y[3]; }
  #pragma unroll
  for(int o=32;o>=1;o>>=1) ssy += __shfl_xor(ssy,o);
  if((tid&63)==0) red[2][tid>>6]=ssy;
  __syncthreads();
  ssy = red[2][0]+red[2][1]+red[2][2]+red[2][3];
  float ry = 1.f/fmaxf(sqrtf(ssy),1e-12f);
  float4 o4; o4.x=y[0]*ry; o4.y=y[1]*ry; o4.z=y[2]*ry; o4.w=y[3]*ry;
  ((float4*)(out + (size_t)row*C_))[tid] = o4;
}

extern "C" void kernel_launch(void* const* d_in, const int* in_sizes, int n_in,
                              void* d_out, int out_size, void* d_ws, size_t ws_size,
                              hipStream_t stream){
  (void)n_in; (void)out_size; (void)ws_size;
  int i_khyp, sphb;
  if (in_sizes[9]==16){ i_khyp=9; sphb=10; } else { i_khyp=13; sphb=9; }
  const float* Wq[3] = {(const float*)d_in[1], (const float*)d_in[5], (const float*)d_in[sphb+0]};
  const float* Wo[3] = {(const float*)d_in[2], (const float*)d_in[6], (const float*)d_in[sphb+1]};
  const float* Wu[3] = {(const float*)d_in[3], (const float*)d_in[7], (const float*)d_in[sphb+2]};
  const float* Wm[3] = {(const float*)d_in[4], (const float*)d_in[8], (const float*)d_in[sphb+3]};
  const float* khyp = (const float*)d_in[i_khyp];
  const float* sqk  = (const float*)d_in[14];
  const float* suv  = (const float*)d_in[15];
  const float* aal  = (const float*)d_in[16];
  const float* mal  = (const float*)d_in[17];

  char* p = (char*)d_ws;
  auto alloc = [&](size_t bytes)->char*{ char* r=p; p += (bytes+255)&~(size_t)255; return r; };
  float* x    = (float*)alloc((size_t)M_*C_*4);
  float* hf32 = (float*)alloc((size_t)M_*C_*4);
  u16* h_bf   = (u16*)alloc((size_t)M_*C_*2);
  u16* qkv    = (u16*)alloc((size_t)M_*3072*2);
  u16* Qb     = (u16*)alloc((size_t)M_*1024*2);
  u16* Kb     = (u16*)alloc((size_t)M_*1024*2);
  u16* Vt     = (u16*)alloc((size_t)M_*1024*2);
  u16* att    = (u16*)alloc((size_t)M_*1024*2);
  u16* uvb    = (u16*)alloc((size_t)M_*8192*2);
  u16* gb     = (u16*)alloc((size_t)M_*4096*2);
  u16* wqb    = (u16*)alloc((size_t)3*C_*C_*2);
  u16* wob    = (u16*)alloc((size_t)C_*C_*2);
  u16* wub    = (u16*)alloc((size_t)8*C_*C_*2);
  u16* wmb    = (u16*)alloc((size_t)4*C_*C_*2);
  float* cosT = (float*)alloc((size_t)T_*32*4);
  float* sinT = (float*)alloc((size_t)T_*32*4);
  // ALIASED onto uvb (32 MB), safe by stream order:
  //  - attn partials: written by attn_split, read by attn_combine, dead before MLP writes uvb
  //  - gemm split-K partials: written by gemm_sk (Wo: after combine; Wmo: after silu
  //    reads uvb is wrong -- silu reads uvb, but Wmo's partials are only written AFTER
  //    k_silu has consumed uvb into gb, and gemm_sk reads gb which is separate)
  float* partO  = (float*)uvb;                       // 2048*4*1024 f32 = 33.6 MB
  float* partML = partO + (size_t)8*1024*1024;       // 1 MB, lands in gb region head... 
  // NOTE: partML must NOT alias gb (gb live during Wmo gemm). Place it in hf32 instead
  // for euc/hyp (hf32 unused there); for sph, hf32 is used -- but attn partML is dead
  // before sph's Wo gemm writes hf32. Use hf32 tail: size 8MB, partML needs 1MB.
  partML = hf32 + (size_t)7*256*1024;                // last 1 MB of hf32 region
  float* partC  = (float*)uvb;                       // split-K gemm partials (<=32MB)

  hipMemcpyAsync(x, d_in[0], (size_t)M_*C_*4, hipMemcpyDeviceToDevice, stream);
  k_tables<<<T_*32/256, 256, 0, stream>>>(cosT, sinT);

  const int MN = M_*C_;   // 2M elems
  for (int gi=0; gi<3; ++gi){
    bool sph = (gi==2);
    k_cast4<<<16384, 256, 0, stream>>>(Wq[gi], Wo[gi], Wu[gi], Wm[gi], wqb, wob, wub, wmb);

    if (!sph) k_rms<1><<<M_,256,0,stream>>>(x, h_bf);
    else      k_rms<0><<<M_,256,0,stream>>>(x, h_bf);
    k_gemm<0><<<dim3(24,16),256,0,stream>>>(h_bf, wqb, qkv, nullptr, M_, 3072, 1024);
    if (sph) k_ropeqk<1><<<8192,256,0,stream>>>(qkv, cosT, sinT, sqk, Qb, Kb);
    else     k_ropeqk<0><<<8192,256,0,stream>>>(qkv, cosT, sinT, nullptr, Qb, Kb);
    k_vtrans<<<dim3(32,16),256,0,stream>>>(qkv, Vt);
    if (gi==0)      k_attn_split<0><<<dim3(64,32,4),64,0,stream>>>(Qb,Kb,Vt,nullptr,partO,partML);
    else if (gi==1) k_attn_split<1><<<dim3(64,32,4),64,0,stream>>>(Qb,Kb,Vt,khyp,partO,partML);
    else            k_attn_split<2><<<dim3(64,32,4),64,0,stream>>>(Qb,Kb,Vt,nullptr,partO,partML);
    k_attn_combine<<<dim3(64,32),64,0,stream>>>(partO, partML, att);

    if (!sph){
      // Wo: split-K=2 (K=1024 -> 2x512), partials in uvb (attn partials dead)
      k_gemm_sk<<<dim3(8,16,2),256,0,stream>>>(att, wob, partC, M_, 1024, 1024, 512);
      k_skred<1,2><<<MN/1024,256,0,stream>>>(partC, x, x, MN);
      k_rms<1><<<M_,256,0,stream>>>(x, h_bf);
      k_gemm<0><<<dim3(64,16),256,0,stream>>>(h_bf, wub, uvb, nullptr, M_, 8192, 1024);
      k_silu<0><<<8192,256,0,stream>>>(uvb, nullptr, gb);
      // Wmo: split-K=4 (K=4096 -> 4x1024); uvb free again (silu consumed it)
      k_gemm_sk<<<dim3(8,16,4),256,0,stream>>>(gb, wmb, partC, M_, 1024, 4096, 1024);
      k_skred<1,4><<<MN/1024,256,0,stream>>>(partC, x, x, MN);
    } else {
      k_gemm_sk<<<dim3(8,16,2),256,0,stream>>>(att, wob, partC, M_, 1024, 1024, 512);
      k_skred<0,2><<<MN/1024,256,0,stream>>>(partC, nullptr, hf32, MN);
      k_sphskip<<<M_,256,0,stream>>>(x, hf32, aal, x);
      k_rms<0><<<M_,256,0,stream>>>(x, h_bf);
      k_gemm<0><<<dim3(64,16),256,0,stream>>>(h_bf, wub, uvb, nullptr, M_, 8192, 1024);
      k_silu<1><<<8192,256,0,stream>>>(uvb, suv, gb);
      k_gemm_sk<<<dim3(8,16,4),256,0,stream>>>(gb, wmb, partC, M_, 1024, 4096, 1024);
      k_skred<0,4><<<MN/1024,256,0,stream>>>(partC, nullptr, hf32, MN);
      k_sphskip<<<M_,256,0,stream>>>(x, hf32, mal, (float*)d_out);
    }
  }
}